// Round 8
// baseline (576.778 us; speedup 1.0000x reference)
//
#include <hip/hip_runtime.h>

// Problem: B=512, T=256, C=384, HS=64.  out = softmax(tril(tanh(x@Ws))) @ (x@Wv)
// with Ws = Wq@Wql + Wk@Wkl  (elementwise add of q_w,k_w collapses: both linear in x).
// Lineage: round-0 VERIFIED kernel (320us) with ONE structural change: Xs is now
// double-buffered, so the K-loop needs ONE __syncthreads per kc instead of two.
// Register structure identical to round 0 (xf[8] single-depth, X+W staged via LDS)
// — rounds 3/7 proved any bulk data in registers spills past the 128-arch-VGPR cap
// (WRITE_SIZE 788-833MB spill signature).  LDS fits by aliasing Vb/scr onto the Xs
// region in the epilogue (Vb=Xs[0]: last read kc=4; scr(w)=Xs[1] block (kk0,rt=w):
// read only by wave w itself, in-wave DS-ordered).
#define BATCH 512
#define TT    256
#define CC    384
#define HH    64

typedef float  f32x4 __attribute__((ext_vector_type(4)));
typedef short  s16x8 __attribute__((ext_vector_type(8)));

// LDS map (bytes)
#define XS_OFF   0        // X chunks [buf2][kk2][rt16][lane64][8] bf16 = 65536
#define WS_OFF   65536    // W chunks [buf2][kk2][ct20][lane64][8] bf16 = 81920
#define VB_OFF   0        // epilogue alias: V blob [vct4][ch8][lane64][8] bf16 = 32768 (= Xs[0])
#define SCR_OFF  32768    // epilogue alias: per-wave scratch 8 x 1024B (= Xs[1] kk0 rt=w blocks)
#define LDS_TOTAL 147456

__device__ __forceinline__ unsigned short f2bf(float f) {
    union { float f; unsigned u; } c; c.f = f;
    unsigned u = c.u;
    u += 0x7fffu + ((u >> 16) & 1u);   // RNE
    return (unsigned short)(u >> 16);
}

// async global->LDS, 16B per lane. HW: wave-uniform base + lane*16 — our dst is
// lane-linear by construction. Casts go through integers (generic->AS3 = low 32 bits).
__device__ __forceinline__ void gld_lds16(const void* g, void* l) {
    __builtin_amdgcn_global_load_lds(
        (const __attribute__((address_space(1))) unsigned int*)(unsigned long long)g,
        (__attribute__((address_space(3))) unsigned int*)(unsigned int)(unsigned long long)l,
        16, 0, 0);
}

// ---------------- Kernel A: build bf16 weight blob in ws ----------------
// Blob: [kc6][kk2][ct20][lane64][j8] bf16.  Element (k in [0,384), n in [0,320)):
//   kc=k>>6, kk=(k>>5)&1, ct=n>>4, lane=((k>>3)&3)*16 + (n&15), j=k&7.
// ct 0..15 = Ws^T (B-frag), ct 16..19 = Wv^T.
__global__ void prep_w(const float* __restrict__ Wq, const float* __restrict__ Wk,
                       const float* __restrict__ Wv, const float* __restrict__ Wql,
                       const float* __restrict__ Wkl, unsigned short* __restrict__ wsW) {
    int gid = blockIdx.x * 256 + threadIdx.x;   // covers 384*256 + 384*64 = 122880
    int k, n; float val;
    if (gid < CC * 256) {
        k = gid >> 8; int s = gid & 255; n = s;
        float acc = 0.f;
        for (int h = 0; h < HH; ++h)
            acc += Wq[k * HH + h] * Wql[h * 256 + s] + Wk[k * HH + h] * Wkl[h * 256 + s];
        val = acc;
    } else {
        int g2 = gid - CC * 256;
        k = g2 >> 6; int h = g2 & 63; n = 256 + h;
        val = Wv[k * HH + h];
    }
    int kc = k >> 6, kk = (k >> 5) & 1, ct = n >> 4;
    int lane = ((k >> 3) & 3) * 16 + (n & 15);
    int j = k & 7;
    wsW[((((kc * 2 + kk) * 20 + ct) * 64) + lane) * 8 + j] = f2bf(val);
}

// ---------------- Kernel B: per-batch fused attention ----------------
__global__ __launch_bounds__(512, 2) void head_main(const float* __restrict__ x,
                                                    const unsigned short* __restrict__ wsW,
                                                    float* __restrict__ out) {
    extern __shared__ char sm[];
    unsigned short* Xs  = (unsigned short*)(sm + XS_OFF);
    unsigned short* Wsh = (unsigned short*)(sm + WS_OFF);
    unsigned short* Vb  = (unsigned short*)(sm + VB_OFF);

    const int b    = blockIdx.x;
    const int t    = threadIdx.x;
    const int w    = (t >> 6) & 7;      // wave 0..7 (&7 so compiler knows range)
    const int lane = t & 63;
    const int q    = lane >> 4;
    const int cidx = lane & 15;
    const int rt0  = w;                 // <= 7
    const int rt1  = 15 - w;            // >= 8
    unsigned short* scr = (unsigned short*)(sm + SCR_OFF) + w * 512;  // 1KB/wave (aliases Xs[1] kk0 rt=w)

    const float* xb = x + (size_t)b * (TT * CC);

    // Accumulators: wave owns row-tiles rt0,rt1 across ALL col-tiles (causal-trimmed).
    f32x4 accS0[8], accS1[16], accV[2][4];
#pragma unroll
    for (int i = 0; i < 8; ++i)  accS0[i] = (f32x4){0.f,0.f,0.f,0.f};
#pragma unroll
    for (int i = 0; i < 16; ++i) accS1[i] = (f32x4){0.f,0.f,0.f,0.f};
#pragma unroll
    for (int i = 0; i < 2; ++i)
#pragma unroll
        for (int j = 0; j < 4; ++j) accV[i][j] = (f32x4){0.f,0.f,0.f,0.f};

    // X cooperative-load address precompute: granule g = t + i*512 of [kk2][rt16][lane64] (16B)
    int xrow[4], xkoff[4];
#pragma unroll
    for (int i = 0; i < 4; ++i) {
        int g = t + i * 512;
        int kk = g >> 10, rt = (g >> 6) & 15, L = g & 63;
        xrow[i]  = rt * 16 + (L & 15);
        xkoff[i] = kk * 32 + ((L >> 4) & 3) * 8;
    }

    float4 xf[8];   // single-depth (32 VGPRs) — do NOT deepen; 2-deep spilled (R7)

    auto loadX = [&](int kcv) {
#pragma unroll
        for (int i = 0; i < 4; ++i) {
            const float4* p = (const float4*)(xb + xrow[i] * CC + kcv * 64 + xkoff[i]);
            xf[2*i]   = p[0];
            xf[2*i+1] = p[1];
        }
    };
    auto storeX = [&](int buf) {
#pragma unroll
        for (int i = 0; i < 4; ++i) {
            int g = t + i * 512;
            float4 f0 = xf[2*i], f1 = xf[2*i+1];
            s16x8 v;
            v[0] = (short)f2bf(f0.x); v[1] = (short)f2bf(f0.y);
            v[2] = (short)f2bf(f0.z); v[3] = (short)f2bf(f0.w);
            v[4] = (short)f2bf(f1.x); v[5] = (short)f2bf(f1.y);
            v[6] = (short)f2bf(f1.z); v[7] = (short)f2bf(f1.w);
            *(s16x8*)(Xs + (buf * 2048 + g) * 8) = v;
        }
    };

    // ---- prologue: X0 -> regs, W0 -> LDS buf0 (async), X0 -> Xs[0] ----
    loadX(0);
#pragma unroll
    for (int i = 0; i < 5; ++i) {
        int g = t + i * 512;
        gld_lds16(wsW + g * 8, Wsh + g * 8);
    }
    storeX(0);         // waits the 8 X loads (W glds may still fly)
    __syncthreads();   // drains W0, publishes Xs[0]

    // ---- K-loop: 6 iterations of BK=64, ONE barrier per kc ----
#pragma unroll
    for (int kc = 0; kc < 6; ++kc) {
        if (kc < 5) {
            loadX(kc + 1);   // 8 global loads, consumed after compute
            const unsigned short* wsrc = wsW + (size_t)(kc + 1) * 20480;
            unsigned short*       wdst = Wsh + ((kc + 1) & 1) * 20480;
#pragma unroll
            for (int i = 0; i < 5; ++i) {
                int g = t + i * 512;
                gld_lds16(wsrc + g * 8, wdst + g * 8);
            }
        }

        // compute chunk kc from Xs[kc&1], Ws[kc&1] — long window hides the loads above
        const unsigned short* Xb = Xs + (kc & 1) * 16384;
        const unsigned short* Wb = Wsh + (kc & 1) * 20480;
#pragma unroll
        for (int kk = 0; kk < 2; ++kk) {
            s16x8 a0 = *(const s16x8*)(Xb + ((kk * 16 + rt0) * 64 + lane) * 8);
            s16x8 a1 = *(const s16x8*)(Xb + ((kk * 16 + rt1) * 64 + lane) * 8);
#pragma unroll
            for (int ct = 0; ct < 16; ++ct) {
                if (ct <= rt1) {           // rt1 >= 8: folds true for ct<=8
                    s16x8 bf = *(const s16x8*)(Wb + ((kk * 20 + ct) * 64 + lane) * 8);
                    accS1[ct] = __builtin_amdgcn_mfma_f32_16x16x32_bf16(a1, bf, accS1[ct], 0, 0, 0);
                    if (ct < 8 && ct <= rt0)
                        accS0[ct] = __builtin_amdgcn_mfma_f32_16x16x32_bf16(a0, bf, accS0[ct], 0, 0, 0);
                }
            }
#pragma unroll
            for (int v2 = 0; v2 < 4; ++v2) {
                s16x8 bf = *(const s16x8*)(Wb + ((kk * 20 + 16 + v2) * 64 + lane) * 8);
                accV[0][v2] = __builtin_amdgcn_mfma_f32_16x16x32_bf16(a0, bf, accV[0][v2], 0, 0, 0);
                accV[1][v2] = __builtin_amdgcn_mfma_f32_16x16x32_bf16(a1, bf, accV[1][v2], 0, 0, 0);
            }
        }

        if (kc < 5) {
            storeX((kc + 1) & 1);   // xf drained here (after compute), into the OTHER buffer
            __syncthreads();        // drains W(kc+1) glds; publishes Xs[(kc+1)&1]
        }
    }
    // after kc=5: no barrier.  Epilogue writes Vb(=Xs[0], last read kc=4) and
    // scr(w)(=Xs[1] kk0 rt=w, read only by wave w itself) — both safe un-barriered.

    // ---- epilogue: E = exp(tanh(S)) masked -> A-frags (via per-wave scratch), V -> Vb, rowsums ----
    float rs0[4] = {0.f,0.f,0.f,0.f}, rs1[4] = {0.f,0.f,0.f,0.f};
    s16x8 pf0[4], pf1[8];

#pragma unroll
    for (int ch = 0; ch < 8; ++ch) {
        if (ch <= (rt1 >> 1)) {
#pragma unroll
            for (int sub = 0; sub < 2; ++sub) {
                const int ct = 2 * ch + sub;
                const int gcol = ct * 16 + cidx;
                const int c = sub * 16 + cidx;
#pragma unroll
                for (int rg = 0; rg < 4; ++rg) {
                    const int grow = rt1 * 16 + q * 4 + rg;
                    float e = 0.f;
                    if (ct <= rt1 && gcol <= grow) {
                        float sv = accS1[2 * ch + sub][rg];
                        float ex = __expf(2.f * sv);
                        float th = 1.f - __fdividef(2.f, ex + 1.f);   // tanh
                        e = __expf(th);                                // bounded -> no max-sub needed
                    }
                    rs1[rg] += e;
                    scr[((c >> 3) * 16 + q * 4 + rg) * 8 + (c & 7)] = f2bf(e);
                }
            }
            pf1[ch] = *(const s16x8*)(scr + lane * 8);   // in-wave DS ordered
        }
    }
#pragma unroll
    for (int ch = 0; ch < 4; ++ch) {
        if (ch <= (rt0 >> 1)) {
#pragma unroll
            for (int sub = 0; sub < 2; ++sub) {
                const int ct = 2 * ch + sub;
                const int gcol = ct * 16 + cidx;
                const int c = sub * 16 + cidx;
#pragma unroll
                for (int rg = 0; rg < 4; ++rg) {
                    const int grow = rt0 * 16 + q * 4 + rg;
                    float e = 0.f;
                    if (ct <= rt0 && gcol <= grow) {
                        float sv = accS0[2 * ch + sub][rg];
                        float ex = __expf(2.f * sv);
                        float th = 1.f - __fdividef(2.f, ex + 1.f);
                        e = __expf(th);
                    }
                    rs0[rg] += e;
                    scr[((c >> 3) * 16 + q * 4 + rg) * 8 + (c & 7)] = f2bf(e);
                }
            }
            pf0[ch] = *(const s16x8*)(scr + lane * 8);
        }
    }

    // V -> Vb (B-frag order for PV)
#pragma unroll
    for (int ri = 0; ri < 2; ++ri) {
        const int rt = ri ? rt1 : rt0;
#pragma unroll
        for (int vct = 0; vct < 4; ++vct)
#pragma unroll
            for (int rg = 0; rg < 4; ++rg) {
                int srow = rt * 16 + q * 4 + rg;
                Vb[((vct * 8 + (srow >> 5)) * 64 + ((srow >> 3) & 3) * 16 + cidx) * 8 + (srow & 7)] =
                    f2bf(accV[ri][vct][rg]);
            }
    }

    // rowsums: reduce across the 16 lanes sharing each row (quad-group), replicated
#pragma unroll
    for (int rg = 0; rg < 4; ++rg) {
        float v0 = rs0[rg], v1 = rs1[rg];
        v0 += __shfl_xor(v0, 1); v0 += __shfl_xor(v0, 2);
        v0 += __shfl_xor(v0, 4); v0 += __shfl_xor(v0, 8);
        v1 += __shfl_xor(v1, 1); v1 += __shfl_xor(v1, 2);
        v1 += __shfl_xor(v1, 4); v1 += __shfl_xor(v1, 8);
        rs0[rg] = v0; rs1[rg] = v1;
    }

    __syncthreads();   // Vb visible to all waves

    // ---- phase 2: out = (E @ V) / rowsum — fully per-wave ----
    f32x4 acc2[2][4];
#pragma unroll
    for (int i = 0; i < 2; ++i)
#pragma unroll
        for (int j = 0; j < 4; ++j) acc2[i][j] = (f32x4){0.f,0.f,0.f,0.f};

    const int nch0 = rt0 >> 1, nch1 = rt1 >> 1;
#pragma unroll
    for (int ch = 0; ch < 8; ++ch) {
        if (ch <= nch1) {
            s16x8 vb[4];
#pragma unroll
            for (int vct = 0; vct < 4; ++vct)
                vb[vct] = *(const s16x8*)(Vb + ((vct * 8 + ch) * 64 + lane) * 8);
#pragma unroll
            for (int vct = 0; vct < 4; ++vct)
                acc2[1][vct] = __builtin_amdgcn_mfma_f32_16x16x32_bf16(pf1[ch], vb[vct], acc2[1][vct], 0, 0, 0);
            if (ch < 4 && ch <= nch0) {
#pragma unroll
                for (int vct = 0; vct < 4; ++vct)
                    acc2[0][vct] = __builtin_amdgcn_mfma_f32_16x16x32_bf16(pf0[ch], vb[vct], acc2[0][vct], 0, 0, 0);
            }
        }
    }

    float* ob = out + (size_t)b * (TT * HH);
#pragma unroll
    for (int ri = 0; ri < 2; ++ri) {
        const int rt = ri ? rt1 : rt0;
#pragma unroll
        for (int rg = 0; rg < 4; ++rg) {
            int row = rt * 16 + q * 4 + rg;
            float inv = __fdividef(1.f, ri ? rs1[rg] : rs0[rg]);
#pragma unroll
            for (int vct = 0; vct < 4; ++vct)
                ob[row * HH + vct * 16 + cidx] = acc2[ri][vct][rg] * inv;
        }
    }
}

extern "C" void kernel_launch(void* const* d_in, const int* in_sizes, int n_in,
                              void* d_out, int out_size, void* d_ws, size_t ws_size,
                              hipStream_t stream) {
    const float* x   = (const float*)d_in[0];
    const float* Wq  = (const float*)d_in[1];
    const float* Wk  = (const float*)d_in[2];
    const float* Wv  = (const float*)d_in[3];
    const float* Wql = (const float*)d_in[4];
    const float* Wkl = (const float*)d_in[5];
    unsigned short* wsW = (unsigned short*)d_ws;   // 245760 B blob
    float* out = (float*)d_out;

    prep_w<<<480, 256, 0, stream>>>(Wq, Wk, Wv, Wql, Wkl, wsW);

    hipFuncSetAttribute((const void*)head_main,
                        hipFuncAttributeMaxDynamicSharedMemorySize, LDS_TOTAL);
    head_main<<<BATCH, 512, LDS_TOTAL, stream>>>(x, wsW, out);
}

// Round 9
// 320.918 us; speedup vs baseline: 1.7973x; 1.7973x over previous
//
#include <hip/hip_runtime.h>

// Problem: B=512, T=256, C=384, HS=64.  out = softmax(tril(tanh(x@Ws))) @ (x@Wv)
// with Ws = Wq@Wql + Wk@Wkl  (elementwise add of q_w,k_w collapses: both linear in x).
// Lineage: round-8 kernel with ONE change: the kc loop is ROLLED (no #pragma unroll).
// Evidence (R0/R1 vs R3/R7/R8): every kernel with an unrolled kc loop spilled
// (~700-800MB scratch WRITE_SIZE, head_main 3x slower) — full unroll lets the
// scheduler overlap all iterations' load live-ranges past the 256-reg unified cap.
// Structure: Xs AND Ws double-buffered -> ONE __syncthreads per kc (R0 had two);
// epilogue aliases Vb onto Xs[0] (last read kc=4, barrier after kc=4) and per-wave
// scr onto Xs[1] block (kk0, rt=w) (only wave w ever reads that block; in-wave
// DS ordering covers write->read).
#define BATCH 512
#define TT    256
#define CC    384
#define HH    64

typedef float  f32x4 __attribute__((ext_vector_type(4)));
typedef short  s16x8 __attribute__((ext_vector_type(8)));

// LDS map (bytes)
#define XS_OFF   0        // X chunks [buf2][kk2][rt16][lane64][8] bf16 = 65536
#define WS_OFF   65536    // W chunks [buf2][kk2][ct20][lane64][8] bf16 = 81920
#define VB_OFF   0        // epilogue alias: V blob [vct4][ch8][lane64][8] bf16 = 32768 (= Xs[0])
#define SCR_OFF  32768    // epilogue alias: per-wave scratch 8 x 1024B (= Xs[1] kk0 rt=w blocks)
#define LDS_TOTAL 147456

__device__ __forceinline__ unsigned short f2bf(float f) {
    union { float f; unsigned u; } c; c.f = f;
    unsigned u = c.u;
    u += 0x7fffu + ((u >> 16) & 1u);   // RNE
    return (unsigned short)(u >> 16);
}

// async global->LDS, 16B per lane. HW: wave-uniform base + lane*16 — our dst is
// lane-linear by construction. Casts go through integers (generic->AS3 = low 32 bits).
__device__ __forceinline__ void gld_lds16(const void* g, void* l) {
    __builtin_amdgcn_global_load_lds(
        (const __attribute__((address_space(1))) unsigned int*)(unsigned long long)g,
        (__attribute__((address_space(3))) unsigned int*)(unsigned int)(unsigned long long)l,
        16, 0, 0);
}

// ---------------- Kernel A: build bf16 weight blob in ws ----------------
// Blob: [kc6][kk2][ct20][lane64][j8] bf16.  Element (k in [0,384), n in [0,320)):
//   kc=k>>6, kk=(k>>5)&1, ct=n>>4, lane=((k>>3)&3)*16 + (n&15), j=k&7.
// ct 0..15 = Ws^T (B-frag), ct 16..19 = Wv^T.
__global__ void prep_w(const float* __restrict__ Wq, const float* __restrict__ Wk,
                       const float* __restrict__ Wv, const float* __restrict__ Wql,
                       const float* __restrict__ Wkl, unsigned short* __restrict__ wsW) {
    int gid = blockIdx.x * 256 + threadIdx.x;   // covers 384*256 + 384*64 = 122880
    int k, n; float val;
    if (gid < CC * 256) {
        k = gid >> 8; int s = gid & 255; n = s;
        float acc = 0.f;
        for (int h = 0; h < HH; ++h)
            acc += Wq[k * HH + h] * Wql[h * 256 + s] + Wk[k * HH + h] * Wkl[h * 256 + s];
        val = acc;
    } else {
        int g2 = gid - CC * 256;
        k = g2 >> 6; int h = g2 & 63; n = 256 + h;
        val = Wv[k * HH + h];
    }
    int kc = k >> 6, kk = (k >> 5) & 1, ct = n >> 4;
    int lane = ((k >> 3) & 3) * 16 + (n & 15);
    int j = k & 7;
    wsW[((((kc * 2 + kk) * 20 + ct) * 64) + lane) * 8 + j] = f2bf(val);
}

// ---------------- Kernel B: per-batch fused attention ----------------
__global__ __launch_bounds__(512, 2) void head_main(const float* __restrict__ x,
                                                    const unsigned short* __restrict__ wsW,
                                                    float* __restrict__ out) {
    extern __shared__ char sm[];
    unsigned short* Xs  = (unsigned short*)(sm + XS_OFF);
    unsigned short* Wsh = (unsigned short*)(sm + WS_OFF);
    unsigned short* Vb  = (unsigned short*)(sm + VB_OFF);

    const int b    = blockIdx.x;
    const int t    = threadIdx.x;
    const int w    = (t >> 6) & 7;      // wave 0..7 (&7 so compiler knows range)
    const int lane = t & 63;
    const int q    = lane >> 4;
    const int cidx = lane & 15;
    const int rt0  = w;                 // <= 7
    const int rt1  = 15 - w;            // >= 8
    unsigned short* scr = (unsigned short*)(sm + SCR_OFF) + w * 512;  // 1KB/wave (aliases Xs[1] kk0 rt=w)

    const float* xb = x + (size_t)b * (TT * CC);

    // Accumulators: wave owns row-tiles rt0,rt1 across ALL col-tiles (causal-trimmed).
    f32x4 accS0[8], accS1[16], accV[2][4];
#pragma unroll
    for (int i = 0; i < 8; ++i)  accS0[i] = (f32x4){0.f,0.f,0.f,0.f};
#pragma unroll
    for (int i = 0; i < 16; ++i) accS1[i] = (f32x4){0.f,0.f,0.f,0.f};
#pragma unroll
    for (int i = 0; i < 2; ++i)
#pragma unroll
        for (int j = 0; j < 4; ++j) accV[i][j] = (f32x4){0.f,0.f,0.f,0.f};

    // X cooperative-load address precompute: granule g = t + i*512 of [kk2][rt16][lane64] (16B)
    int xrow[4], xkoff[4];
#pragma unroll
    for (int i = 0; i < 4; ++i) {
        int g = t + i * 512;
        int kk = g >> 10, rt = (g >> 6) & 15, L = g & 63;
        xrow[i]  = rt * 16 + (L & 15);
        xkoff[i] = kk * 32 + ((L >> 4) & 3) * 8;
    }

    float4 xf[8];   // single-depth (32 VGPRs)

    auto loadX = [&](int kcv) {
#pragma unroll
        for (int i = 0; i < 4; ++i) {
            const float4* p = (const float4*)(xb + xrow[i] * CC + kcv * 64 + xkoff[i]);
            xf[2*i]   = p[0];
            xf[2*i+1] = p[1];
        }
    };
    auto storeX = [&](int buf) {
#pragma unroll
        for (int i = 0; i < 4; ++i) {
            int g = t + i * 512;
            float4 f0 = xf[2*i], f1 = xf[2*i+1];
            s16x8 v;
            v[0] = (short)f2bf(f0.x); v[1] = (short)f2bf(f0.y);
            v[2] = (short)f2bf(f0.z); v[3] = (short)f2bf(f0.w);
            v[4] = (short)f2bf(f1.x); v[5] = (short)f2bf(f1.y);
            v[6] = (short)f2bf(f1.z); v[7] = (short)f2bf(f1.w);
            *(s16x8*)(Xs + (buf * 2048 + g) * 8) = v;
        }
    };

    // ---- prologue: X0 -> regs, W0 -> LDS buf0 (async), X0 -> Xs[0] ----
    loadX(0);
#pragma unroll
    for (int i = 0; i < 5; ++i) {
        int g = t + i * 512;
        gld_lds16(wsW + g * 8, Wsh + g * 8);
    }
    storeX(0);         // waits the 8 X loads (W glds may still fly)
    __syncthreads();   // drains W0, publishes Xs[0]

    // ---- K-loop: 6 iterations of BK=64, ONE barrier per kc.  ROLLED (no unroll
    // pragma): full unroll let the scheduler overlap iterations' load live-ranges
    // past the 256-reg cap -> 700-800MB scratch spill (R3/R7/R8 evidence).
    for (int kc = 0; kc < 6; ++kc) {
        if (kc < 5) {
            loadX(kc + 1);   // 8 global loads, consumed after compute
            const unsigned short* wsrc = wsW + (size_t)(kc + 1) * 20480;
            unsigned short*       wdst = Wsh + ((kc + 1) & 1) * 20480;
#pragma unroll
            for (int i = 0; i < 5; ++i) {
                int g = t + i * 512;
                gld_lds16(wsrc + g * 8, wdst + g * 8);
            }
        }

        // compute chunk kc from Xs[kc&1], Ws[kc&1] — long window hides the loads above
        const unsigned short* Xb = Xs + (kc & 1) * 16384;
        const unsigned short* Wb = Wsh + (kc & 1) * 20480;
#pragma unroll
        for (int kk = 0; kk < 2; ++kk) {
            s16x8 a0 = *(const s16x8*)(Xb + ((kk * 16 + rt0) * 64 + lane) * 8);
            s16x8 a1 = *(const s16x8*)(Xb + ((kk * 16 + rt1) * 64 + lane) * 8);
#pragma unroll
            for (int ct = 0; ct < 16; ++ct) {
                if (ct <= rt1) {           // rt1 >= 8: folds true for ct<=8
                    s16x8 bf = *(const s16x8*)(Wb + ((kk * 20 + ct) * 64 + lane) * 8);
                    accS1[ct] = __builtin_amdgcn_mfma_f32_16x16x32_bf16(a1, bf, accS1[ct], 0, 0, 0);
                    if (ct < 8 && ct <= rt0)
                        accS0[ct] = __builtin_amdgcn_mfma_f32_16x16x32_bf16(a0, bf, accS0[ct], 0, 0, 0);
                }
            }
#pragma unroll
            for (int v2 = 0; v2 < 4; ++v2) {
                s16x8 bf = *(const s16x8*)(Wb + ((kk * 20 + 16 + v2) * 64 + lane) * 8);
                accV[0][v2] = __builtin_amdgcn_mfma_f32_16x16x32_bf16(a0, bf, accV[0][v2], 0, 0, 0);
                accV[1][v2] = __builtin_amdgcn_mfma_f32_16x16x32_bf16(a1, bf, accV[1][v2], 0, 0, 0);
            }
        }

        if (kc < 5) {
            storeX((kc + 1) & 1);   // xf drained here (after compute), into the OTHER buffer
            __syncthreads();        // drains W(kc+1) glds; publishes Xs[(kc+1)&1]
        }
    }
    // after kc=5: no barrier.  Epilogue writes Vb(=Xs[0], last read kc=4, barrier
    // after kc=4) and scr(w)(=Xs[1] kk0 rt=w, read only by wave w itself).

    // ---- epilogue: E = exp(tanh(S)) masked -> A-frags (via per-wave scratch), V -> Vb, rowsums ----
    float rs0[4] = {0.f,0.f,0.f,0.f}, rs1[4] = {0.f,0.f,0.f,0.f};
    s16x8 pf0[4], pf1[8];

#pragma unroll
    for (int ch = 0; ch < 8; ++ch) {
        if (ch <= (rt1 >> 1)) {
#pragma unroll
            for (int sub = 0; sub < 2; ++sub) {
                const int ct = 2 * ch + sub;
                const int gcol = ct * 16 + cidx;
                const int c = sub * 16 + cidx;
#pragma unroll
                for (int rg = 0; rg < 4; ++rg) {
                    const int grow = rt1 * 16 + q * 4 + rg;
                    float e = 0.f;
                    if (ct <= rt1 && gcol <= grow) {
                        float sv = accS1[2 * ch + sub][rg];
                        float ex = __expf(2.f * sv);
                        float th = 1.f - __fdividef(2.f, ex + 1.f);   // tanh
                        e = __expf(th);                                // bounded -> no max-sub needed
                    }
                    rs1[rg] += e;
                    scr[((c >> 3) * 16 + q * 4 + rg) * 8 + (c & 7)] = f2bf(e);
                }
            }
            pf1[ch] = *(const s16x8*)(scr + lane * 8);   // in-wave DS ordered
        }
    }
#pragma unroll
    for (int ch = 0; ch < 4; ++ch) {
        if (ch <= (rt0 >> 1)) {
#pragma unroll
            for (int sub = 0; sub < 2; ++sub) {
                const int ct = 2 * ch + sub;
                const int gcol = ct * 16 + cidx;
                const int c = sub * 16 + cidx;
#pragma unroll
                for (int rg = 0; rg < 4; ++rg) {
                    const int grow = rt0 * 16 + q * 4 + rg;
                    float e = 0.f;
                    if (ct <= rt0 && gcol <= grow) {
                        float sv = accS0[2 * ch + sub][rg];
                        float ex = __expf(2.f * sv);
                        float th = 1.f - __fdividef(2.f, ex + 1.f);
                        e = __expf(th);
                    }
                    rs0[rg] += e;
                    scr[((c >> 3) * 16 + q * 4 + rg) * 8 + (c & 7)] = f2bf(e);
                }
            }
            pf0[ch] = *(const s16x8*)(scr + lane * 8);
        }
    }

    // V -> Vb (B-frag order for PV)
#pragma unroll
    for (int ri = 0; ri < 2; ++ri) {
        const int rt = ri ? rt1 : rt0;
#pragma unroll
        for (int vct = 0; vct < 4; ++vct)
#pragma unroll
            for (int rg = 0; rg < 4; ++rg) {
                int srow = rt * 16 + q * 4 + rg;
                Vb[((vct * 8 + (srow >> 5)) * 64 + ((srow >> 3) & 3) * 16 + cidx) * 8 + (srow & 7)] =
                    f2bf(accV[ri][vct][rg]);
            }
    }

    // rowsums: reduce across the 16 lanes sharing each row (quad-group), replicated
#pragma unroll
    for (int rg = 0; rg < 4; ++rg) {
        float v0 = rs0[rg], v1 = rs1[rg];
        v0 += __shfl_xor(v0, 1); v0 += __shfl_xor(v0, 2);
        v0 += __shfl_xor(v0, 4); v0 += __shfl_xor(v0, 8);
        v1 += __shfl_xor(v1, 1); v1 += __shfl_xor(v1, 2);
        v1 += __shfl_xor(v1, 4); v1 += __shfl_xor(v1, 8);
        rs0[rg] = v0; rs1[rg] = v1;
    }

    __syncthreads();   // Vb visible to all waves

    // ---- phase 2: out = (E @ V) / rowsum — fully per-wave ----
    f32x4 acc2[2][4];
#pragma unroll
    for (int i = 0; i < 2; ++i)
#pragma unroll
        for (int j = 0; j < 4; ++j) acc2[i][j] = (f32x4){0.f,0.f,0.f,0.f};

    const int nch0 = rt0 >> 1, nch1 = rt1 >> 1;
#pragma unroll
    for (int ch = 0; ch < 8; ++ch) {
        if (ch <= nch1) {
            s16x8 vb[4];
#pragma unroll
            for (int vct = 0; vct < 4; ++vct)
                vb[vct] = *(const s16x8*)(Vb + ((vct * 8 + ch) * 64 + lane) * 8);
#pragma unroll
            for (int vct = 0; vct < 4; ++vct)
                acc2[1][vct] = __builtin_amdgcn_mfma_f32_16x16x32_bf16(pf1[ch], vb[vct], acc2[1][vct], 0, 0, 0);
            if (ch < 4 && ch <= nch0) {
#pragma unroll
                for (int vct = 0; vct < 4; ++vct)
                    acc2[0][vct] = __builtin_amdgcn_mfma_f32_16x16x32_bf16(pf0[ch], vb[vct], acc2[0][vct], 0, 0, 0);
            }
        }
    }

    float* ob = out + (size_t)b * (TT * HH);
#pragma unroll
    for (int ri = 0; ri < 2; ++ri) {
        const int rt = ri ? rt1 : rt0;
#pragma unroll
        for (int rg = 0; rg < 4; ++rg) {
            int row = rt * 16 + q * 4 + rg;
            float inv = __fdividef(1.f, ri ? rs1[rg] : rs0[rg]);
#pragma unroll
            for (int vct = 0; vct < 4; ++vct)
                ob[row * HH + vct * 16 + cidx] = acc2[ri][vct][rg] * inv;
        }
    }
}

extern "C" void kernel_launch(void* const* d_in, const int* in_sizes, int n_in,
                              void* d_out, int out_size, void* d_ws, size_t ws_size,
                              hipStream_t stream) {
    const float* x   = (const float*)d_in[0];
    const float* Wq  = (const float*)d_in[1];
    const float* Wk  = (const float*)d_in[2];
    const float* Wv  = (const float*)d_in[3];
    const float* Wql = (const float*)d_in[4];
    const float* Wkl = (const float*)d_in[5];
    unsigned short* wsW = (unsigned short*)d_ws;   // 245760 B blob
    float* out = (float*)d_out;

    prep_w<<<480, 256, 0, stream>>>(Wq, Wk, Wv, Wql, Wkl, wsW);

    hipFuncSetAttribute((const void*)head_main,
                        hipFuncAttributeMaxDynamicSharedMemorySize, LDS_TOTAL);
    head_main<<<BATCH, 512, LDS_TOTAL, stream>>>(x, wsW, out);
}